// Round 3
// baseline (310.329 us; speedup 1.0000x reference)
//
#include <hip/hip_runtime.h>
#include <hip/hip_bf16.h>

#define NB 8192     // batch
#define IC 32       // input capsules
#define ID 288      // input dims (K)
#define OD16 160    // OUT_CAPS*OUT_DIMS (N)

typedef __attribute__((ext_vector_type(8))) short bf16x8;
typedef __attribute__((ext_vector_type(4))) float f32x4;

__device__ __forceinline__ unsigned short f2bf(float f) {
    unsigned int u = __builtin_bit_cast(unsigned int, f);
    u = u + 0x7fffu + ((u >> 16) & 1u);   // round-to-nearest-even
    return (unsigned short)(u >> 16);
}
__device__ __forceinline__ float bf2f(unsigned short h) {
    return __builtin_bit_cast(float, ((unsigned int)h) << 16);
}
// 8 floats -> 8 bf16 via v_cvt_pk_bf16_f32 (compiler-generated)
__device__ __forceinline__ bf16x8 cvt_bf8(const float4& a, const float4& b) {
    union { __hip_bfloat162 h[4]; bf16x8 v; } u;
    u.h[0] = __float22bfloat162_rn(make_float2(a.x, a.y));
    u.h[1] = __float22bfloat162_rn(make_float2(a.z, a.w));
    u.h[2] = __float22bfloat162_rn(make_float2(b.x, b.y));
    u.h[3] = __float22bfloat162_rn(make_float2(b.z, b.w));
    return u.v;
}

__device__ __forceinline__ void gld_lds16(const void* g, void* l) {
    __builtin_amdgcn_global_load_lds((const __attribute__((address_space(1))) unsigned int*)g,
                                     (__attribute__((address_space(3))) unsigned int*)l, 16, 0, 0);
}

// ---------------------------------------------------------------------------
// prep: one block per (c, s). LDS-transpose W's [kw x 160] f32 tile into
// bf16, then emit the "LDS image" WtImg[c][s][10240 shorts]: linear byte b
// holds granule (n = b>>7, g = ((b>>4)&7) ^ (n&7)) so that a linear
// global_load_lds write + XOR-swizzled ds_read in gemm reconstructs B.
// K padded 288->320 with zeros. Block 0 additionally zeros a_part[3][8][320].
// ---------------------------------------------------------------------------
__global__ __launch_bounds__(256) void prep_kernel(const float* __restrict__ W,
                                                   unsigned short* __restrict__ WtImg,
                                                   float* __restrict__ a_arr) {
    __shared__ short tile[160 * 72];   // row n: 64 k-shorts (+pad), 144B stride
    const int bx = blockIdx.x;
    const int c = bx / 5;
    const int s = bx - c * 5;
    const int t = threadIdx.x;
    if (bx == 0) {
        for (int i = t; i < 3 * 8 * 320; i += 256) a_arr[i] = 0.f;
    }
    const int kw = (s == 4) ? 32 : 64;
    const int nel = kw * 160;
    for (int idx = t; idx < nel; idx += 256) {
        int k = idx / 160;
        int n = idx - k * 160;
        tile[n * 72 + k] = (short)f2bf(W[((long)c * ID + s * 64 + k) * OD16 + n]);
    }
    __syncthreads();
    unsigned short* dst = WtImg + ((long)c * 5 + s) * 10240;
    for (int p = t; p < 1280; p += 256) {
        int n = p >> 3;
        int g = (p & 7) ^ (n & 7);
        uint4 val = make_uint4(0u, 0u, 0u, 0u);
        if (g * 8 < kw) val = *(const uint4*)&tile[n * 72 + g * 8];
        *(uint4*)(dst + p * 8) = val;
    }
}

// ---------------------------------------------------------------------------
// gemm: u_hat[b][c][od] = data[b][c][:] @ W[c][:][od], bf16 MFMA 16x16x32.
// Block 256 thr (4 waves), tile 128(M) x 160(N), BK=64, 5 stages (K pad 320).
// A: direct global->reg fragment loads. B: double-buffered LDS via
// global_load_lds. One barrier per stage. Epilogue staged through LDS.
// ---------------------------------------------------------------------------
__global__ __launch_bounds__(256, 4) void gemm_kernel(const float* __restrict__ data,
                                                      const unsigned short* __restrict__ WtImg,
                                                      unsigned short* __restrict__ uhat) {
    __shared__ alignas(16) char Bb[2][20480];
    const int tid = threadIdx.x;
    const int lane = tid & 63;
    const int w = tid >> 6;
    const int q = lane >> 4;     // 0..3
    const int r = lane & 15;
    const int b0 = blockIdx.x * 128;
    const int cc = blockIdx.y;

    const float* A0 = data + (long)(b0 + w * 32 + r) * (IC * ID) + cc * ID;  // mf=0 row
    const float* A1 = A0 + 16 * (IC * ID);                                   // mf=1 row
    const unsigned short* Wc = WtImg + (long)cc * 51200;

    f32x4 acc[2][10];
    #pragma unroll
    for (int i = 0; i < 2; ++i)
        #pragma unroll
        for (int j = 0; j < 10; ++j)
            acc[i][j] = (f32x4){0.f, 0.f, 0.f, 0.f};

    auto issueB = [&](int buf, int s) {
        const unsigned short* src = Wc + s * 10240 + (w * 5) * 512 + lane * 8;
        char* dst = &Bb[buf][(w * 5) * 1024];
        #pragma unroll
        for (int j = 0; j < 5; ++j)
            gld_lds16(src + j * 512, dst + j * 1024);
    };

    int cur = 0;
    issueB(0, 0);
    __syncthreads();

    for (int s = 0; s < 5; ++s) {
        if (s < 4) issueB(cur ^ 1, s + 1);   // next-stage DMA in flight over compute
        const int nkc = (s == 4) ? 1 : 2;
        float4 av[2][2][2];   // [mf][kc][half]
        #pragma unroll
        for (int kc = 0; kc < 2; ++kc) {
            if (kc < nkc) {
                const int k = s * 64 + kc * 32 + q * 8;
                av[0][kc][0] = *(const float4*)(A0 + k);
                av[0][kc][1] = *(const float4*)(A0 + k + 4);
                av[1][kc][0] = *(const float4*)(A1 + k);
                av[1][kc][1] = *(const float4*)(A1 + k + 4);
            }
        }
        #pragma unroll
        for (int kc = 0; kc < 2; ++kc) {
            if (kc < nkc) {
                const int kb = kc * 64 + q * 16;   // byte offset within 128B row
                bf16x8 bfr[10];
                #pragma unroll
                for (int nf = 0; nf < 10; ++nf) {
                    const int n = nf * 16 + r;
                    bfr[nf] = *(const bf16x8*)(&Bb[cur][(n * 128 + kb) ^ ((n & 7) << 4)]);
                }
                bf16x8 af[2];
                af[0] = cvt_bf8(av[0][kc][0], av[0][kc][1]);
                af[1] = cvt_bf8(av[1][kc][0], av[1][kc][1]);
                #pragma unroll
                for (int mf = 0; mf < 2; ++mf)
                    #pragma unroll
                    for (int nf = 0; nf < 10; ++nf)
                        acc[mf][nf] = __builtin_amdgcn_mfma_f32_16x16x32_bf16(af[mf], bfr[nf], acc[mf][nf], 0, 0, 0);
            }
        }
        __syncthreads();
        cur ^= 1;
    }

    // epilogue: C/D layout col=lane&15 (N), row=q*4+reg (M)
    short* eb = (short*)&Bb[0][0];   // [128][160] shorts = 40960B
    #pragma unroll
    for (int mf = 0; mf < 2; ++mf)
        #pragma unroll
        for (int rr = 0; rr < 4; ++rr) {
            const int m = w * 32 + mf * 16 + (q << 2) + rr;
            #pragma unroll
            for (int nf = 0; nf < 10; ++nf)
                eb[m * 160 + nf * 16 + r] = (short)f2bf(acc[mf][nf][rr]);
        }
    __syncthreads();
    #pragma unroll
    for (int j = 0; j < 10; ++j) {
        const int chunk = j * 256 + tid;
        const int row = chunk / 20;
        const int p = chunk - row * 20;
        *(uint4*)(uhat + (long)(b0 + row) * (IC * OD16) + cc * OD16 + p * 8) =
            *(const uint4*)(eb + row * 160 + p * 8);
    }
}

// ---------------------------------------------------------------------------
// route: one wave per batch row, grid 2048x256 (8192 waves exactly).
// Softmax over i from 8-way-spread a partials. Agreement-phase u fragments
// preloaded to registers (overlaps v-phase); v-phase reads u from global
// (coalesced); v shared across wave via tiny LDS; per-wave a partials
// block-reduced in LDS, then 320 atomics/block onto a_out[blockIdx&7].
// ---------------------------------------------------------------------------
template <int COMPUTE_A, int WRITE_V>
__global__ __launch_bounds__(256) void route_kernel(const unsigned short* __restrict__ uhat,
                                                    const float* __restrict__ a_all,  // [n_prev][8][320]
                                                    int n_prev,
                                                    float* __restrict__ a_out,        // [8][320]
                                                    float* __restrict__ v_out) {
    __shared__ float c_sh[320];
    __shared__ float v_lds[4][160];
    __shared__ float a_sh[4][320];
    const int tid = threadIdx.x;
    // --- softmax over input capsules (groups of 32, lane-aligned) ---
    for (int base = 0; base < 320; base += 256) {
        int t = base + tid;
        if (t < 320) {
            float bv = 0.f;
            for (int j = 0; j < n_prev * 8; ++j) bv += a_all[j * 320 + t];
            bv *= (1.0f / 8192.0f);
            float m = bv;
            #pragma unroll
            for (int off = 1; off < 32; off <<= 1) m = fmaxf(m, __shfl_xor(m, off));
            float e = __expf(bv - m);
            float ssum = e;
            #pragma unroll
            for (int off = 1; off < 32; off <<= 1) ssum += __shfl_xor(ssum, off);
            c_sh[t] = e / ssum;
        }
    }
    __syncthreads();

    const int w = tid >> 6;
    const int lane = tid & 63;
    const long row = (long)blockIdx.x * 4 + w;
    const unsigned short* __restrict__ u = uhat + row * (IC * OD16);

    // preload agreement fragments: lane -> (i = lane&31, oo = (lane>>5)+2*s5)
    ushort4 ua[5][4];
    if (COMPUTE_A) {
        #pragma unroll
        for (int s5 = 0; s5 < 5; ++s5) {
            const int i = lane & 31;
            const int oo = (lane >> 5) + 2 * s5;
            #pragma unroll
            for (int d4 = 0; d4 < 4; ++d4)
                ua[s5][d4] = *(const ushort4*)(u + i * 160 + oo * 16 + d4 * 4);
        }
    }

    // v-phase: lanes 0..39, lane q owns od-quad q
    if (lane < 40) {
        const int q = lane;
        const int o = q >> 2;
        float4 sv = {0.f, 0.f, 0.f, 0.f};
        #pragma unroll 8
        for (int i = 0; i < 32; ++i) {
            ushort4 uu = *(const ushort4*)(u + i * 160 + q * 4);
            float ci = c_sh[o * 32 + i];
            sv.x += ci * bf2f(uu.x);
            sv.y += ci * bf2f(uu.y);
            sv.z += ci * bf2f(uu.z);
            sv.w += ci * bf2f(uu.w);
        }
        if (WRITE_V) *(float4*)(v_out + row * 160 + q * 4) = sv;
        if (COMPUTE_A) *(float4*)(&v_lds[w][q * 4]) = sv;
    }

    if (COMPUTE_A) {
        asm volatile("s_waitcnt lgkmcnt(0)" ::: "memory");  // v_lds visible wave-locally
        #pragma unroll
        for (int s5 = 0; s5 < 5; ++s5) {
            const int i = lane & 31;
            const int oo = (lane >> 5) + 2 * s5;
            const float* vp = &v_lds[w][oo * 16];
            float accv = 0.f;
            #pragma unroll
            for (int d4 = 0; d4 < 4; ++d4) {
                ushort4 uu = ua[s5][d4];
                float4 vv = *(const float4*)(vp + d4 * 4);
                float p0 = bf2f(uu.x) * vv.x;
                float p1 = bf2f(uu.y) * vv.y;
                float p2 = bf2f(uu.z) * vv.z;
                float p3 = bf2f(uu.w) * vv.w;
                accv += p0 * p0 + p1 * p1 + p2 * p2 + p3 * p3;
            }
            a_sh[w][oo * 32 + i] = sqrtf(accv);
        }
        __syncthreads();
        for (int t = tid; t < 320; t += 256) {
            float s4 = a_sh[0][t] + a_sh[1][t] + a_sh[2][t] + a_sh[3][t];
            atomicAdd(a_out + (blockIdx.x & 7) * 320 + t, s4);
        }
    }
}

// ---------------------------------------------------------------------------
extern "C" void kernel_launch(void* const* d_in, const int* in_sizes, int n_in,
                              void* d_out, int out_size, void* d_ws, size_t ws_size,
                              hipStream_t stream) {
    const float* data = (const float*)d_in[0];
    const float* W = (const float*)d_in[1];
    float* out = (float*)d_out;
    char* ws = (char*)d_ws;

    unsigned short* uhat = (unsigned short*)ws;           // 83,886,080 B
    size_t off = (size_t)NB * IC * OD16 * 2;
    unsigned short* WtImg = (unsigned short*)(ws + off);  // 3,276,800 B
    off += 32L * 5 * 10240 * 2;
    float* a_arr = (float*)(ws + off); off += 3 * 8 * 320 * 4;  // [it][8][320]

    hipLaunchKernelGGL(prep_kernel, dim3(160), dim3(256), 0, stream, W, WtImg, a_arr);
    hipLaunchKernelGGL(gemm_kernel, dim3(64, 32), dim3(256), 0, stream, data, WtImg, uhat);
    hipLaunchKernelGGL((route_kernel<1, 0>), dim3(2048), dim3(256), 0, stream,
                       uhat, a_arr, 0, a_arr + 0 * 2560, out);
    hipLaunchKernelGGL((route_kernel<1, 0>), dim3(2048), dim3(256), 0, stream,
                       uhat, a_arr, 1, a_arr + 1 * 2560, out);
    hipLaunchKernelGGL((route_kernel<0, 1>), dim3(2048), dim3(256), 0, stream,
                       uhat, a_arr, 2, a_arr + 2 * 2560, out);
}

// Round 4
// 194.157 us; speedup vs baseline: 1.5983x; 1.5983x over previous
//
#include <hip/hip_runtime.h>
#include <hip/hip_bf16.h>

#define NB 8192     // batch
#define IC 32       // input capsules
#define ID 288      // input dims (K)
#define OD16 160    // OUT_CAPS*OUT_DIMS (N)

typedef __attribute__((ext_vector_type(8))) short bf16x8;
typedef __attribute__((ext_vector_type(4))) float f32x4;

__device__ __forceinline__ unsigned short f2bf(float f) {
    unsigned int u = __builtin_bit_cast(unsigned int, f);
    u = u + 0x7fffu + ((u >> 16) & 1u);   // round-to-nearest-even
    return (unsigned short)(u >> 16);
}
__device__ __forceinline__ float bf2f(unsigned short h) {
    return __builtin_bit_cast(float, ((unsigned int)h) << 16);
}
// 8 floats -> 8 bf16 via v_cvt_pk_bf16_f32 (compiler-generated)
__device__ __forceinline__ bf16x8 cvt_bf8(const float4& a, const float4& b) {
    union { __hip_bfloat162 h[4]; bf16x8 v; } u;
    u.h[0] = __float22bfloat162_rn(make_float2(a.x, a.y));
    u.h[1] = __float22bfloat162_rn(make_float2(a.z, a.w));
    u.h[2] = __float22bfloat162_rn(make_float2(b.x, b.y));
    u.h[3] = __float22bfloat162_rn(make_float2(b.z, b.w));
    return u.v;
}

__device__ __forceinline__ void gld_lds16(const void* g, void* l) {
    __builtin_amdgcn_global_load_lds((const __attribute__((address_space(1))) unsigned int*)g,
                                     (__attribute__((address_space(3))) unsigned int*)l, 16, 0, 0);
}

// ---------------------------------------------------------------------------
// prep: one block per (c, s). LDS-transpose W's [kw x 160] f32 tile into
// bf16, emit the "LDS image" WtImg[c][s][10240 shorts] (linear DMA dest +
// XOR-swizzled ds_read reconstructs B). K padded 288->320 with zeros.
// Block 0 additionally zeros a_part[3][8][320].
// ---------------------------------------------------------------------------
__global__ __launch_bounds__(256) void prep_kernel(const float* __restrict__ W,
                                                   unsigned short* __restrict__ WtImg,
                                                   float* __restrict__ a_arr) {
    __shared__ short tile[160 * 72];   // row n: 64 k-shorts (+pad), 144B stride
    const int bx = blockIdx.x;
    const int c = bx / 5;
    const int s = bx - c * 5;
    const int t = threadIdx.x;
    if (bx == 0) {
        for (int i = t; i < 3 * 8 * 320; i += 256) a_arr[i] = 0.f;
    }
    const int kw = (s == 4) ? 32 : 64;
    const int nel = kw * 160;
    for (int idx = t; idx < nel; idx += 256) {
        int k = idx / 160;
        int n = idx - k * 160;
        tile[n * 72 + k] = (short)f2bf(W[((long)c * ID + s * 64 + k) * OD16 + n]);
    }
    __syncthreads();
    unsigned short* dst = WtImg + ((long)c * 5 + s) * 10240;
    for (int p = t; p < 1280; p += 256) {
        int n = p >> 3;
        int g = (p & 7) ^ (n & 7);
        uint4 val = make_uint4(0u, 0u, 0u, 0u);
        if (g * 8 < kw) val = *(const uint4*)&tile[n * 72 + g * 8];
        *(uint4*)(dst + p * 8) = val;
    }
}

// ---------------------------------------------------------------------------
// gemm: u_hat[c][b][od] = data[b][c][:] @ W[c][:][od], bf16 MFMA 16x16x32.
// Software-pipelined: A double-buffered in registers, B double-buffered in
// LDS via global_load_lds; counted vmcnt + raw s_barrier (no vmcnt(0) drain
// in the loop) so next-stage loads stay in flight across barriers.
// ---------------------------------------------------------------------------
__global__ __launch_bounds__(256) void gemm_kernel(const float* __restrict__ data,
                                                   const unsigned short* __restrict__ WtImg,
                                                   unsigned short* __restrict__ uhat) {
    __shared__ alignas(16) char Bb[2][20480];
    const int tid = threadIdx.x;
    const int lane = tid & 63;
    const int w = tid >> 6;
    const int q = lane >> 4;     // 0..3
    const int r = lane & 15;
    const int b0 = blockIdx.x * 128;
    const int cc = blockIdx.y;

    const float* A0 = data + (long)(b0 + w * 32 + r) * (IC * ID) + cc * ID;  // mf=0 row
    const float* A1 = A0 + 16 * (IC * ID);                                   // mf=1 row
    const unsigned short* Wc = WtImg + (long)cc * 51200;

    f32x4 acc[2][10];
    #pragma unroll
    for (int i = 0; i < 2; ++i)
        #pragma unroll
        for (int j = 0; j < 10; ++j)
            acc[i][j] = (f32x4){0.f, 0.f, 0.f, 0.f};

    float4 av[2][2][2][2];   // [bank][mf][kc][half] -- all constant-indexed

    auto issueB = [&](int buf, int s) {
        const unsigned short* src = Wc + s * 10240 + (w * 5) * 512 + lane * 8;
        char* dst = &Bb[buf][(w * 5) * 1024];
        #pragma unroll
        for (int j = 0; j < 5; ++j)
            gld_lds16(src + j * 512, dst + j * 1024);
    };

#define ISSUEA(BANK, S, NKC)                                                   \
    {                                                                          \
        _Pragma("unroll")                                                      \
        for (int kc = 0; kc < (NKC); ++kc) {                                   \
            const int k = (S) * 64 + kc * 32 + q * 8;                          \
            av[BANK][0][kc][0] = *(const float4*)(A0 + k);                     \
            av[BANK][0][kc][1] = *(const float4*)(A0 + k + 4);                 \
            av[BANK][1][kc][0] = *(const float4*)(A1 + k);                     \
            av[BANK][1][kc][1] = *(const float4*)(A1 + k + 4);                 \
        }                                                                      \
    }

#define COMPUTE(BANK, CUR, NKC)                                                \
    {                                                                          \
        _Pragma("unroll")                                                      \
        for (int kc = 0; kc < (NKC); ++kc) {                                   \
            const int kb = kc * 64 + q * 16;                                   \
            bf16x8 bfr[10];                                                    \
            _Pragma("unroll")                                                  \
            for (int nf = 0; nf < 10; ++nf) {                                  \
                const int n = nf * 16 + r;                                     \
                bfr[nf] = *(const bf16x8*)(&Bb[CUR][(n * 128 + kb) ^ ((n & 7) << 4)]); \
            }                                                                  \
            bf16x8 af0 = cvt_bf8(av[BANK][0][kc][0], av[BANK][0][kc][1]);      \
            bf16x8 af1 = cvt_bf8(av[BANK][1][kc][0], av[BANK][1][kc][1]);      \
            _Pragma("unroll")                                                  \
            for (int nf = 0; nf < 10; ++nf) {                                  \
                acc[0][nf] = __builtin_amdgcn_mfma_f32_16x16x32_bf16(af0, bfr[nf], acc[0][nf], 0, 0, 0); \
                acc[1][nf] = __builtin_amdgcn_mfma_f32_16x16x32_bf16(af1, bfr[nf], acc[1][nf], 0, 0, 0); \
            }                                                                  \
        }                                                                      \
    }

// Per stage: issue next A+B, wait own (A(s),B(s)) via counted vmcnt, barrier
// (=> all waves' B(s) DMA landed), read/compute, barrier (close W-after-R epoch).
#define STAGE(S, BANK, CUR, NKC, NKC_NEXT, WAIT)                               \
    {                                                                          \
        if ((S) < 4) { ISSUEA(1 - (BANK), (S) + 1, NKC_NEXT); issueB(1 - (CUR), (S) + 1); } \
        asm volatile("s_waitcnt vmcnt(" WAIT ")" ::: "memory");                \
        __builtin_amdgcn_s_barrier();                                          \
        __builtin_amdgcn_sched_barrier(0);                                     \
        COMPUTE(BANK, CUR, NKC);                                               \
        if ((S) < 4) __builtin_amdgcn_s_barrier();                             \
    }

    ISSUEA(0, 0, 2);
    issueB(0, 0);

    STAGE(0, 0, 0, 2, 2, "13")
    STAGE(1, 1, 1, 2, 2, "13")
    STAGE(2, 0, 0, 2, 2, "13")
    STAGE(3, 1, 1, 2, 1, "9")
    STAGE(4, 0, 0, 1, 0, "0")

#undef STAGE
#undef COMPUTE
#undef ISSUEA

    // epilogue: C/D layout col=lane&15 (N), row=q*4+reg (M). Stage through
    // LDS, then fully contiguous 40KB store (uhat layout [c][b][od]).
    __syncthreads();
    short* eb = (short*)&Bb[0][0];   // [128][160] shorts = 40960B
    #pragma unroll
    for (int mf = 0; mf < 2; ++mf)
        #pragma unroll
        for (int rr = 0; rr < 4; ++rr) {
            const int m = w * 32 + mf * 16 + (q << 2) + rr;
            #pragma unroll
            for (int nf = 0; nf < 10; ++nf)
                eb[m * 160 + nf * 16 + r] = (short)f2bf(acc[mf][nf][rr]);
        }
    __syncthreads();
    unsigned short* dstc = uhat + ((long)cc * NB + b0) * 160;
    #pragma unroll
    for (int j = 0; j < 10; ++j) {
        const int chunk = j * 256 + tid;
        *(uint4*)(dstc + chunk * 8) = *(const uint4*)(eb + chunk * 8);
    }
}

// ---------------------------------------------------------------------------
// route: one wave per batch row, grid 2048x256. uhat layout [i][b][od]
// (plane stride PL). Softmax from 8-way-spread a partials; agreement u
// fragments preloaded to regs (overlap v-phase); v via tiny LDS; block-
// reduced a partials -> 320 atomics/block onto a_out[blockIdx&7].
// ---------------------------------------------------------------------------
template <int COMPUTE_A, int WRITE_V>
__global__ __launch_bounds__(256) void route_kernel(const unsigned short* __restrict__ uhat,
                                                    const float* __restrict__ a_all,  // [n_prev][8][320]
                                                    int n_prev,
                                                    float* __restrict__ a_out,        // [8][320]
                                                    float* __restrict__ v_out) {
    constexpr long PL = (long)NB * 160;   // i-plane stride (shorts)
    __shared__ float c_sh[320];
    __shared__ float v_lds[4][160];
    __shared__ float a_sh[4][320];
    const int tid = threadIdx.x;
    // --- softmax over input capsules (groups of 32, lane-aligned) ---
    for (int base = 0; base < 320; base += 256) {
        int t = base + tid;
        if (t < 320) {
            float bv = 0.f;
            for (int j = 0; j < n_prev * 8; ++j) bv += a_all[j * 320 + t];
            bv *= (1.0f / 8192.0f);
            float m = bv;
            #pragma unroll
            for (int off = 1; off < 32; off <<= 1) m = fmaxf(m, __shfl_xor(m, off));
            float e = __expf(bv - m);
            float ssum = e;
            #pragma unroll
            for (int off = 1; off < 32; off <<= 1) ssum += __shfl_xor(ssum, off);
            c_sh[t] = e / ssum;
        }
    }
    __syncthreads();

    const int w = tid >> 6;
    const int lane = tid & 63;
    const long row = (long)blockIdx.x * 4 + w;
    const unsigned short* __restrict__ u = uhat + row * 160;

    // preload agreement fragments: lane -> (i = lane&31, oo = (lane>>5)+2*s5)
    ushort4 ua[5][4];
    if (COMPUTE_A) {
        #pragma unroll
        for (int s5 = 0; s5 < 5; ++s5) {
            const int i = lane & 31;
            const int oo = (lane >> 5) + 2 * s5;
            #pragma unroll
            for (int d4 = 0; d4 < 4; ++d4)
                ua[s5][d4] = *(const ushort4*)(u + (long)i * PL + oo * 16 + d4 * 4);
        }
    }

    // v-phase: lanes 0..39, lane q owns od-quad q
    if (lane < 40) {
        const int q = lane;
        const int o = q >> 2;
        float4 sv = {0.f, 0.f, 0.f, 0.f};
        #pragma unroll 8
        for (int i = 0; i < 32; ++i) {
            ushort4 uu = *(const ushort4*)(u + (long)i * PL + q * 4);
            float ci = c_sh[o * 32 + i];
            sv.x += ci * bf2f(uu.x);
            sv.y += ci * bf2f(uu.y);
            sv.z += ci * bf2f(uu.z);
            sv.w += ci * bf2f(uu.w);
        }
        if (WRITE_V) *(float4*)(v_out + row * 160 + q * 4) = sv;
        if (COMPUTE_A) *(float4*)(&v_lds[w][q * 4]) = sv;
    }

    if (COMPUTE_A) {
        asm volatile("s_waitcnt lgkmcnt(0)" ::: "memory");  // v_lds visible wave-locally
        #pragma unroll
        for (int s5 = 0; s5 < 5; ++s5) {
            const int i = lane & 31;
            const int oo = (lane >> 5) + 2 * s5;
            const float* vp = &v_lds[w][oo * 16];
            float accv = 0.f;
            #pragma unroll
            for (int d4 = 0; d4 < 4; ++d4) {
                ushort4 uu = ua[s5][d4];
                float4 vv = *(const float4*)(vp + d4 * 4);
                float p0 = bf2f(uu.x) * vv.x;
                float p1 = bf2f(uu.y) * vv.y;
                float p2 = bf2f(uu.z) * vv.z;
                float p3 = bf2f(uu.w) * vv.w;
                accv += p0 * p0 + p1 * p1 + p2 * p2 + p3 * p3;
            }
            a_sh[w][oo * 32 + i] = sqrtf(accv);
        }
        __syncthreads();
        for (int t = tid; t < 320; t += 256) {
            float s4 = a_sh[0][t] + a_sh[1][t] + a_sh[2][t] + a_sh[3][t];
            atomicAdd(a_out + (blockIdx.x & 7) * 320 + t, s4);
        }
    }
}

// ---------------------------------------------------------------------------
extern "C" void kernel_launch(void* const* d_in, const int* in_sizes, int n_in,
                              void* d_out, int out_size, void* d_ws, size_t ws_size,
                              hipStream_t stream) {
    const float* data = (const float*)d_in[0];
    const float* W = (const float*)d_in[1];
    float* out = (float*)d_out;
    char* ws = (char*)d_ws;

    unsigned short* uhat = (unsigned short*)ws;           // [32][8192][160] bf16, 83,886,080 B
    size_t off = (size_t)NB * IC * OD16 * 2;
    unsigned short* WtImg = (unsigned short*)(ws + off);  // 3,276,800 B
    off += 32L * 5 * 10240 * 2;
    float* a_arr = (float*)(ws + off); off += 3 * 8 * 320 * 4;  // [it][8][320]

    hipLaunchKernelGGL(prep_kernel, dim3(160), dim3(256), 0, stream, W, WtImg, a_arr);
    hipLaunchKernelGGL(gemm_kernel, dim3(64, 32), dim3(256), 0, stream, data, WtImg, uhat);
    hipLaunchKernelGGL((route_kernel<1, 0>), dim3(2048), dim3(256), 0, stream,
                       uhat, a_arr, 0, a_arr + 0 * 2560, out);
    hipLaunchKernelGGL((route_kernel<1, 0>), dim3(2048), dim3(256), 0, stream,
                       uhat, a_arr, 1, a_arr + 1 * 2560, out);
    hipLaunchKernelGGL((route_kernel<0, 1>), dim3(2048), dim3(256), 0, stream,
                       uhat, a_arr, 2, a_arr + 2 * 2560, out);
}